// Round 4
// baseline (166.515 us; speedup 1.0000x reference)
//
#include <hip/hip_runtime.h>

#define NNODES 50000
#define NEDGES 800000
#define HD 128            // HEADS*OUT_DIM
#define NEG 0.2f
#define MTILE 64
#define LDW 136           // bf16 row stride in LDS
#define GEMMB ((NNODES + MTILE - 1) / MTILE) // 782
#define NBINS 196         // ceil(NNODES/256) coarse bins (dst>>8)
#define CAP 5120          // per-bin cbuf capacity (mean 4082, +16 sigma)
#define GST 16            // gcnt line-padding stride
#define ABLK ((NEDGES + 2047) / 2048)        // 391 bucket blocks
#define ECAP 1536         // per-quarter LDS edge capacity (mean 1020, +16 sigma)

typedef __attribute__((ext_vector_type(8))) short short8;
typedef __attribute__((ext_vector_type(4))) float floatx4;

static __device__ inline unsigned short f2bf(float f) {
    unsigned u = __float_as_uint(f);
    return (unsigned short)((u + 0x7FFF + ((u >> 16) & 1)) >> 16);
}
static __device__ inline float bf2f(unsigned short u) {
    return __uint_as_float(((unsigned)u) << 16);
}
static __device__ inline float lrelu_exp(float a) {
    a = (a > 0.f) ? a : NEG * a;
    return __expf(a);
}

// ---------------------------------------------------------------------------
// Kernel 1: blocks [0,GEMMB) = 64-row GEMM tile (bf16 MFMA, fused asrc/adst
// dots). Blocks [GEMMB,GEMMB+ABLK) = coarse bucketing: LDS-private 196-bin
// histogram over dst>>8, one global atomic per (block,bin), scatter packed
// (fine<<16|src) 4B entries into the bin window (src < 65536 fits 16 bits).
// ---------------------------------------------------------------------------
__global__ __launch_bounds__(256, 4) void gat_main(
    const float* __restrict__ x, const float* __restrict__ W,
    const float* __restrict__ att_src, const float* __restrict__ att_dst,
    const int* __restrict__ ei,
    unsigned short* __restrict__ h, float* __restrict__ asrc,
    float* __restrict__ adst, int* __restrict__ gcnt, int* __restrict__ cbuf)
{
    __shared__ unsigned short Wl[128 * LDW];          // 34816 B
    const int t = threadIdx.x;

    if (blockIdx.x >= GEMMB) {      // ---- coarse bucketing path ----
        int* hist = (int*)Wl;       // [256] reuse gemm LDS
        int* boff = hist + 256;     // [256]
        const int e0 = (blockIdx.x - GEMMB) * 2048 + t * 8;
        const bool act = (e0 < NEDGES);
        int4 s0 = make_int4(0, 0, 0, 0), s1 = s0, d0 = s0, d1 = s0;
        if (act) {
            s0 = *(const int4*)(ei + e0);
            s1 = *(const int4*)(ei + e0 + 4);
            d0 = *(const int4*)(ei + NEDGES + e0);
            d1 = *(const int4*)(ei + NEDGES + e0 + 4);
        }
        hist[t] = 0;
        __syncthreads();
        if (act) {
            atomicAdd(&hist[d0.x >> 8], 1); atomicAdd(&hist[d0.y >> 8], 1);
            atomicAdd(&hist[d0.z >> 8], 1); atomicAdd(&hist[d0.w >> 8], 1);
            atomicAdd(&hist[d1.x >> 8], 1); atomicAdd(&hist[d1.y >> 8], 1);
            atomicAdd(&hist[d1.z >> 8], 1); atomicAdd(&hist[d1.w >> 8], 1);
        }
        __syncthreads();
        if (t < NBINS && hist[t] > 0)
            boff[t] = atomicAdd(&gcnt[t * GST], hist[t]);
        __syncthreads();
        if (act) {
            int ss[8] = {s0.x, s0.y, s0.z, s0.w, s1.x, s1.y, s1.z, s1.w};
            int dd[8] = {d0.x, d0.y, d0.z, d0.w, d1.x, d1.y, d1.z, d1.w};
#pragma unroll
            for (int j = 0; j < 8; j++) {
                int b = dd[j] >> 8;
                int slot = atomicAdd(&boff[b], 1);      // LDS atomic
                cbuf[(size_t)b * CAP + slot] = ((dd[j] & 255) << 16) | ss[j];
            }
        }
        return;
    }

    // ---- GEMM path ----
    const int rowBase = blockIdx.x * MTILE;

    // W stage: fp32 -> bf16 into LDS
    for (int idx = t * 8; idx < 128 * 128; idx += 2048) {
        int r = idx >> 7, c = idx & 127;
        float4 v0 = *(const float4*)(W + idx);
        float4 v1 = *(const float4*)(W + idx + 4);
        short8 u;
        u[0] = (short)f2bf(v0.x); u[1] = (short)f2bf(v0.y);
        u[2] = (short)f2bf(v0.z); u[3] = (short)f2bf(v0.w);
        u[4] = (short)f2bf(v1.x); u[5] = (short)f2bf(v1.y);
        u[6] = (short)f2bf(v1.z); u[7] = (short)f2bf(v1.w);
        *(short8*)(Wl + r * LDW + c) = u;
    }

    // x A-fragments: global -> registers
    const int wave = t >> 6;
    const int lane = t & 63;
    const int c16  = lane & 15;
    const int quad = lane >> 4;
    const int xr   = rowBase + wave * 16 + c16;
    short8 av[4];
#pragma unroll
    for (int kc = 0; kc < 4; kc++) {
        float4 v0 = make_float4(0.f, 0.f, 0.f, 0.f);
        float4 v1 = v0;
        if (xr < NNODES) {
            const float* p = x + (size_t)xr * 128 + kc * 32 + quad * 8;
            v0 = *(const float4*)p;
            v1 = *(const float4*)(p + 4);
        }
        short8 u;
        u[0] = (short)f2bf(v0.x); u[1] = (short)f2bf(v0.y);
        u[2] = (short)f2bf(v0.z); u[3] = (short)f2bf(v0.w);
        u[4] = (short)f2bf(v1.x); u[5] = (short)f2bf(v1.y);
        u[6] = (short)f2bf(v1.z); u[7] = (short)f2bf(v1.w);
        av[kc] = u;
    }
    __syncthreads();

    floatx4 acc[8];
#pragma unroll
    for (int nt = 0; nt < 8; nt++) acc[nt] = (floatx4)(0.f);

#pragma unroll
    for (int kc = 0; kc < 4; kc++) {
#pragma unroll
        for (int nt = 0; nt < 8; nt++) {
            short8 bv = *(const short8*)(Wl + (nt * 16 + c16) * LDW + kc * 32 + quad * 8);
            acc[nt] = __builtin_amdgcn_mfma_f32_16x16x32_bf16(av[kc], bv, acc[nt], 0, 0, 0);
        }
    }

    float As[8], Ad[8];
#pragma unroll
    for (int nt = 0; nt < 8; nt++) {
        As[nt] = att_src[nt * 16 + c16];
        Ad[nt] = att_dst[nt * 16 + c16];
    }
#pragma unroll
    for (int r = 0; r < 4; r++) {
        const int gr = rowBase + wave * 16 + quad * 4 + r;
#pragma unroll
        for (int hh = 0; hh < 4; hh++) {
            float ps = acc[2 * hh][r] * As[2 * hh] + acc[2 * hh + 1][r] * As[2 * hh + 1];
            float pd = acc[2 * hh][r] * Ad[2 * hh] + acc[2 * hh + 1][r] * Ad[2 * hh + 1];
#pragma unroll
            for (int m = 8; m >= 1; m >>= 1) {
                ps += __shfl_xor(ps, m, 64);
                pd += __shfl_xor(pd, m, 64);
            }
            if (c16 == 0 && gr < NNODES) {
                asrc[gr * 4 + hh] = ps;
                adst[gr * 4 + hh] = pd;
            }
        }
    }

    // epilogue: C bounce through Wl for 16B coalesced h stores
    __syncthreads();
#pragma unroll
    for (int r = 0; r < 4; r++) {
        const int lr = wave * 16 + quad * 4 + r;
#pragma unroll
        for (int nt = 0; nt < 8; nt++)
            Wl[lr * LDW + nt * 16 + c16] = f2bf(acc[nt][r]);
    }
    __syncthreads();
    for (int idx = t * 8; idx < MTILE * 128; idx += 2048) {
        int r = idx >> 7, c = idx & 127;
        int g = rowBase + r;
        if (g < NNODES)
            *(short8*)(h + (size_t)g * HD + c) = *(const short8*)(Wl + r * LDW + c);
    }
}

// ---------------------------------------------------------------------------
// Kernel 2 (fused bin+node): 4 sub-blocks per coarse bin, 64 nodes each.
// Per sub-block: 64-bin LDS histogram over the bin window -> wave scan ->
// scatter packed srcs into a 3KB LDS edge list grouped by node. Then 8 groups
// of 32 lanes aggregate 8 nodes each straight from LDS: phase 1 computes exp
// weights (stashed in LDS) + per-head sums -> rsumr[n]; phase 2 gathers h
// rows and accumulates out. No global CSR/coff, no scattered writes.
// ---------------------------------------------------------------------------
__global__ __launch_bounds__(256) void gat_fuse(
    const int* __restrict__ gcnt, const int* __restrict__ cbuf,
    const float* __restrict__ asrc, const float* __restrict__ adst,
    const unsigned short* __restrict__ h, const float* __restrict__ bias,
    float* __restrict__ out, float* __restrict__ rsumr)
{
    __shared__ unsigned short eb[ECAP];     // packed src per edge
    __shared__ float sh_w[ECAP * 4];        // exp weights per edge
    __shared__ int hist[64], run[64], beg[65];
    const int t = threadIdx.x;
    const int b = blockIdx.x >> 2;          // coarse bin
    const int q = blockIdx.x & 3;           // node quarter within bin
    const int c_b = gcnt[b * GST];
    const size_t wbase = (size_t)b * CAP;

    if (t < 64) hist[t] = 0;
    __syncthreads();
    // pass 1: histogram of our quarter (fine>>6 == q)
    for (int i = t; i < c_b; i += 256) {
        int e = cbuf[wbase + i];
        int f = (e >> 16) & 255;
        if ((f >> 6) == q) atomicAdd(&hist[f & 63], 1);
    }
    __syncthreads();
    // wave-0 exclusive scan of hist[64]
    if (t < 64) {
        int v = hist[t];
        int s = v;
#pragma unroll
        for (int off = 1; off < 64; off <<= 1) {
            int u = __shfl_up(s, off, 64);
            if (t >= off) s += u;
        }
        beg[t] = s - v;
        run[t] = s - v;
        if (t == 63) beg[64] = s;
    }
    __syncthreads();
    // pass 2: place srcs grouped by node
    for (int i = t; i < c_b; i += 256) {
        int e = cbuf[wbase + i];
        int f = (e >> 16) & 255;
        if ((f >> 6) == q) {
            int slot = atomicAdd(&run[f & 63], 1);
            if (slot < ECAP) eb[slot] = (unsigned short)(e & 0xFFFF);
        }
    }
    __syncthreads();

    // aggregation: 8 groups x 32 lanes, 8 nodes per group
    const int grp  = t >> 5;
    const int k    = t & 31;
    const int head = k >> 3;
    const float4 bias4 = *(const float4*)(bias + k * 4);

    for (int ii = 0; ii < 8; ii++) {
        const int local = grp * 8 + ii;
        const int n = b * 256 + q * 64 + local;
        int eB = beg[local], eE = beg[local + 1];
        if (eE > ECAP) eE = ECAP;
        if (eB > ECAP) eB = ECAP;

        float4 bn = make_float4(0.f, 0.f, 0.f, 0.f);
        if (n < NNODES) bn = *(const float4*)(adst + n * 4);

        // phase 1: exp weights + per-head sums, stash in LDS
        float4 sum = make_float4(0.f, 0.f, 0.f, 0.f);
        for (int j = eB + k; j < eE; j += 32) {
            int s = eb[j];
            float4 a = *(const float4*)(asrc + s * 4);
            float4 wv;
            wv.x = lrelu_exp(a.x + bn.x);
            wv.y = lrelu_exp(a.y + bn.y);
            wv.z = lrelu_exp(a.z + bn.z);
            wv.w = lrelu_exp(a.w + bn.w);
            sum.x += wv.x; sum.y += wv.y; sum.z += wv.z; sum.w += wv.w;
            *(float4*)(sh_w + j * 4) = wv;
        }
#pragma unroll
        for (int m = 16; m >= 1; m >>= 1) {      // stays within 32-lane group
            sum.x += __shfl_xor(sum.x, m, 64);
            sum.y += __shfl_xor(sum.y, m, 64);
            sum.z += __shfl_xor(sum.z, m, 64);
            sum.w += __shfl_xor(sum.w, m, 64);
        }
        float rs[4];
        rs[0] = 1.f / (sum.x + 1e-16f);
        rs[1] = 1.f / (sum.y + 1e-16f);
        rs[2] = 1.f / (sum.z + 1e-16f);
        rs[3] = 1.f / (sum.w + 1e-16f);
        if (n < NNODES && k == 0) {
            float4 r4 = make_float4(rs[0], rs[1], rs[2], rs[3]);
            *(float4*)(rsumr + n * 4) = r4;
        }
        const float rsel = rs[head];

        // phase 2: gather h rows, 4-way unrolled
        float4 acc = bias4;
        float4 acc2 = make_float4(0.f, 0.f, 0.f, 0.f);
        int i = eB;
        for (; i + 4 <= eE; i += 4) {
            int s0 = eb[i];
            int s1 = eb[i + 1];
            int s2 = eb[i + 2];
            int s3 = eb[i + 3];
            float w0 = sh_w[i * 4 + head] * rsel;
            float w1 = sh_w[(i + 1) * 4 + head] * rsel;
            float w2 = sh_w[(i + 2) * 4 + head] * rsel;
            float w3 = sh_w[(i + 3) * 4 + head] * rsel;
            ushort4 u0 = *(const ushort4*)(h + (size_t)s0 * HD + k * 4);
            ushort4 u1 = *(const ushort4*)(h + (size_t)s1 * HD + k * 4);
            ushort4 u2 = *(const ushort4*)(h + (size_t)s2 * HD + k * 4);
            ushort4 u3 = *(const ushort4*)(h + (size_t)s3 * HD + k * 4);
            acc.x  = fmaf(bf2f(u0.x), w0, acc.x);
            acc.y  = fmaf(bf2f(u0.y), w0, acc.y);
            acc.z  = fmaf(bf2f(u0.z), w0, acc.z);
            acc.w  = fmaf(bf2f(u0.w), w0, acc.w);
            acc2.x = fmaf(bf2f(u1.x), w1, acc2.x);
            acc2.y = fmaf(bf2f(u1.y), w1, acc2.y);
            acc2.z = fmaf(bf2f(u1.z), w1, acc2.z);
            acc2.w = fmaf(bf2f(u1.w), w1, acc2.w);
            acc.x  = fmaf(bf2f(u2.x), w2, acc.x);
            acc.y  = fmaf(bf2f(u2.y), w2, acc.y);
            acc.z  = fmaf(bf2f(u2.z), w2, acc.z);
            acc.w  = fmaf(bf2f(u2.w), w2, acc.w);
            acc2.x = fmaf(bf2f(u3.x), w3, acc2.x);
            acc2.y = fmaf(bf2f(u3.y), w3, acc2.y);
            acc2.z = fmaf(bf2f(u3.z), w3, acc2.z);
            acc2.w = fmaf(bf2f(u3.w), w3, acc2.w);
        }
        for (; i < eE; i++) {
            int s0 = eb[i];
            float w0 = sh_w[i * 4 + head] * rsel;
            ushort4 u0 = *(const ushort4*)(h + (size_t)s0 * HD + k * 4);
            acc.x = fmaf(bf2f(u0.x), w0, acc.x);
            acc.y = fmaf(bf2f(u0.y), w0, acc.y);
            acc.z = fmaf(bf2f(u0.z), w0, acc.z);
            acc.w = fmaf(bf2f(u0.w), w0, acc.w);
        }
        acc.x += acc2.x; acc.y += acc2.y; acc.z += acc2.z; acc.w += acc2.w;
        if (n < NNODES)
            *(float4*)(out + (size_t)n * HD + k * 4) = acc;
    }
}

// ---------------------------------------------------------------------------
// Kernel 3: alpha_pooled, edge order, fully coalesced writes. Gathers come
// from asrc/adst/rsumr (0.8 MB each, L2-resident).
// ---------------------------------------------------------------------------
static __device__ inline float apool1(
    int s, int d, const float* __restrict__ asrc,
    const float* __restrict__ adst, const float* __restrict__ rsumr)
{
    float4 a = *(const float4*)(asrc + s * 4);
    float4 b = *(const float4*)(adst + d * 4);
    float4 r = *(const float4*)(rsumr + d * 4);
    return 0.25f * (lrelu_exp(a.x + b.x) * r.x + lrelu_exp(a.y + b.y) * r.y +
                    lrelu_exp(a.z + b.z) * r.z + lrelu_exp(a.w + b.w) * r.w);
}

__global__ __launch_bounds__(256) void gat_apool(
    const int* __restrict__ ei, const float* __restrict__ asrc,
    const float* __restrict__ adst, const float* __restrict__ rsumr,
    float* __restrict__ apool)
{
    int e0 = (blockIdx.x * 256 + threadIdx.x) * 4;
    if (e0 >= NEDGES) return;
    int4 s = *(const int4*)(ei + e0);
    int4 d = *(const int4*)(ei + NEDGES + e0);
    float4 r;
    r.x = apool1(s.x, d.x, asrc, adst, rsumr);
    r.y = apool1(s.y, d.y, asrc, adst, rsumr);
    r.z = apool1(s.z, d.z, asrc, adst, rsumr);
    r.w = apool1(s.w, d.w, asrc, adst, rsumr);
    *(float4*)(apool + e0) = r;
}

// ---------------------------------------------------------------------------
extern "C" void kernel_launch(void* const* d_in, const int* in_sizes, int n_in,
                              void* d_out, int out_size, void* d_ws, size_t ws_size,
                              hipStream_t stream)
{
    const float* x       = (const float*)d_in[0];
    const int*   ei      = (const int*)d_in[1];
    const float* W       = (const float*)d_in[2];
    const float* att_src = (const float*)d_in[3];
    const float* att_dst = (const float*)d_in[4];
    const float* bias    = (const float*)d_in[5];

    float* out   = (float*)d_out;                    // (N,128)
    float* apool = out + (size_t)NNODES * HD;        // (E,)

    // workspace layout
    unsigned short* h = (unsigned short*)d_ws;            // N*128 bf16
    float* asrc  = (float*)(h + (size_t)NNODES * HD);     // N*4
    float* adst  = asrc + NNODES * 4;                     // N*4
    float* rsumr = adst + NNODES * 4;                     // N*4
    int*   gcnt  = (int*)(rsumr + NNODES * 4);            // NBINS*GST
    int*   cbuf  = gcnt + NBINS * GST;                    // NBINS*CAP ints

    hipMemsetAsync(gcnt, 0, (size_t)NBINS * GST * sizeof(int), stream);

    gat_main<<<GEMMB + ABLK, 256, 0, stream>>>(
        x, W, att_src, att_dst, ei, h, asrc, adst, gcnt, cbuf);
    gat_fuse<<<NBINS * 4, 256, 0, stream>>>(
        gcnt, cbuf, asrc, adst, h, bias, out, rsumr);
    gat_apool<<<(NEDGES / 4 + 255) / 256, 256, 0, stream>>>(
        ei, asrc, adst, rsumr, apool);
}